// Round 10
// baseline (699.482 us; speedup 1.0000x reference)
//
#include <hip/hip_runtime.h>
#include <hip/hip_bf16.h>

typedef short s16x8 __attribute__((ext_vector_type(8)));
typedef float f32x4 __attribute__((ext_vector_type(4)));
typedef unsigned short u16;
typedef unsigned int u32;

#define TB 64
#define NTHREADS 1024

// prep-buffer element offsets (bf16 elements)
#define P_L1 0
#define P_L2 16384
#define P_L3 278528
#define P_L4 540672
#define P_H1 802816
#define P_H2 1327104
#define P_H3 1392640
#define P_H4 1409024
#define P_TOT 1413120

// LDS byte offsets
// h   [64][1024B] at 0..64K (rows 32-63 reused as y1_3 after last H1 K-loop)
// xs  [64][128B]  at 64K..72K (dead after L3 epilogue; overlaid by y1_0)
// y1: p0 at 64K, p1 at 96K, p2 at 128K, p3 at 32K   (each [64][512B])
// H2+ scratch: in-place inside each wave's private y1 slice
#define H_OFF   0
#define XS_OFF  65536
#define LDS_BYTES 163840  // 160 KB

__device__ __forceinline__ u16 f2bf(float v) {
  __hip_bfloat16 b = __float2bfloat16(v);
  return __builtin_bit_cast(u16, b);
}
__device__ __forceinline__ float bf2f(u16 u) {
  u32 x = ((u32)u) << 16;
  return __builtin_bit_cast(float, x);
}

// load one wave's B fragments for a K32 unit straight into registers
template<int FN>
__device__ __forceinline__ void loadB(s16x8 (&b)[FN], const char* unit,
                                      int nCols, int bColBase, int kg, int l15) {
#pragma unroll
  for (int fj = 0; fj < FN; ++fj) {
    const int n = bColBase + fj * 16 + l15;
    b[fj] = *reinterpret_cast<const s16x8*>(unit + (kg * nCols + n) * 16);
  }
}

// one K32 step: read A frags from LDS, FM*FN MFMAs with B regs.
// MFMA via inline asm with "+a" so the ACCUMULATOR LIVES IN AGPRs:
// at 16 waves/block (4 waves/SIMD) the unified-file budget is 128/wave and
// arch-VGPR granularity is 64|128, so acc-in-arch forces 64 arch + spill
// (R6-R8: ~600 MB/dispatch scratch). acc-in-AGPR: ~50 arch + 32 AGPR = fits.
template<int FM, int FN>
__device__ __forceinline__ void mfma_step(
    const char* lds, int aOff, int aRB, int kByte, int mBase, int l15,
    const s16x8 (&b)[FN], f32x4 (&acc)[FM][FN]) {
  s16x8 a[FM];
#pragma unroll
  for (int fi = 0; fi < FM; ++fi) {
    const int m = mBase + fi * 16 + l15;
    a[fi] = *reinterpret_cast<const s16x8*>(
        lds + aOff + m * aRB + (kByte ^ (((m & 7) << 4) & (aRB - 1))));
  }
#pragma unroll
  for (int fi = 0; fi < FM; ++fi)
#pragma unroll
    for (int fj = 0; fj < FN; ++fj)
      asm volatile("v_mfma_f32_16x16x32_bf16 %0, %1, %2, %0"
                   : "+a"(acc[fi][fj])
                   : "v"(a[fi]), "v"(b[fj]));
}

// barrier-free K-loop GEMM: A from LDS, B global->regs (named 2-deep dbuf)
template<int FM, int FN, int KSTEPS>
__device__ __forceinline__ void gemm_reg(
    const char* lds, int aOff, int aRB, int aColBase, int mBase,
    const char* bGlob, int unitStride, int nCols, int bColBase,
    int kg, int l15, f32x4 (&acc)[FM][FN]) {
#pragma unroll
  for (int i = 0; i < FM; ++i)
#pragma unroll
    for (int j = 0; j < FN; ++j) { f32x4 z = {0.f,0.f,0.f,0.f}; acc[i][j] = z; }
  s16x8 bA[FN], bB[FN];
  loadB<FN>(bA, bGlob, nCols, bColBase, kg, l15);
#pragma unroll
  for (int ks = 0; ks < KSTEPS; ks += 2) {
    if (ks + 1 < KSTEPS)
      loadB<FN>(bB, bGlob + (size_t)(ks + 1) * unitStride, nCols, bColBase, kg, l15);
    mfma_step<FM, FN>(lds, aOff, aRB, (aColBase + ks * 32 + kg * 8) * 2,
                      mBase, l15, bA, acc);
    if (ks + 1 < KSTEPS) {
      if (ks + 2 < KSTEPS)
        loadB<FN>(bA, bGlob + (size_t)(ks + 2) * unitStride, nCols, bColBase, kg, l15);
      mfma_step<FM, FN>(lds, aOff, aRB, (aColBase + (ks + 1) * 32 + kg * 8) * 2,
                        mBase, l15, bB, acc);
    }
  }
}

// backbone epilogue (16 waves, fn2): bias (+relu) (+concat relu(xs)) -> h
__device__ __forceinline__ void epi_bb(char* lds, const f32x4 (&acc)[4][2],
    const float* bias, int biasLim, bool relu, bool concatXS,
    int wid, int l15, int rgrp)
{
#pragma unroll
  for (int fj = 0; fj < 2; ++fj) {
    const int gc = wid * 32 + fj * 16 + l15;
    const float bv = (gc < biasLim) ? bias[gc] : 0.f;
#pragma unroll
    for (int fi = 0; fi < 4; ++fi) {
#pragma unroll
      for (int r = 0; r < 4; ++r) {
        const int m = fi * 16 + rgrp * 4 + r;
        float v = acc[fi][fj][r] + bv;
        if (relu) v = fmaxf(v, 0.f);
        u16 hv = f2bf(v);
        if (concatXS && gc >= 482) {
          const int c2 = gc - 482;
          const float xv = bf2f(*reinterpret_cast<const u16*>(
              lds + XS_OFF + m * 128 + ((c2 * 2) ^ ((m & 7) << 4))));
          hv = f2bf(fmaxf(xv, 0.f));
        }
        *reinterpret_cast<u16*>(lds + H_OFF + m * 1024 + ((gc * 2) ^ ((m & 7) << 4))) = hv;
      }
    }
  }
}

// ---------------- weight prep: fp32 -> bf16 [kg][n][8j] packets ----------------
__global__ __launch_bounds__(256)
void prep_weights(const float* __restrict__ W1, const float* __restrict__ W2,
                  const float* __restrict__ W3, const float* __restrict__ W4,
                  const float* __restrict__ HW1, const float* __restrict__ HW2,
                  const float* __restrict__ HW3, const float* __restrict__ HW4,
                  u16* __restrict__ wp)
{
  for (int idx = blockIdx.x * blockDim.x + threadIdx.x; idx < P_TOT;
       idx += gridDim.x * blockDim.x) {
    float v;
    if (idx < P_L2) {                       // L1: 1 unit [kg4][512n][8], K pad 30->32
      const int e = idx;
      const int kg = e >> 12, n = (e >> 3) & 511, j = e & 7;
      const int k = kg * 8 + j;
      v = (k < 30) ? W1[k * 512 + n] : 0.f;
    } else if (idx < P_L3) {                // L2: 16 units of 16384 elems
      const int e = idx - P_L2;
      const int u = e >> 14, r = e & 16383;
      const int kg = r >> 12, n = (r >> 3) & 511, j = r & 7;
      const int k = u * 32 + kg * 8 + j;
      v = W2[k * 512 + n];
    } else if (idx < P_L4) {                // L3 (cols >= 482 zero)
      const int e = idx - P_L3;
      const int u = e >> 14, r = e & 16383;
      const int kg = r >> 12, n = (r >> 3) & 511, j = r & 7;
      const int k = u * 32 + kg * 8 + j;
      v = (n < 482) ? W3[k * 482 + n] : 0.f;
    } else if (idx < P_H1) {                // L4
      const int e = idx - P_L4;
      const int u = e >> 14, r = e & 16383;
      const int kg = r >> 12, n = (r >> 3) & 511, j = r & 7;
      const int k = u * 32 + kg * 8 + j;
      v = W4[k * 512 + n];
    } else if (idx < P_H2) {                // H1: 4 pairs x 16 units [kg4][256n][8]
      const int e = idx - P_H1;
      const int p = e >> 17, r = e & 131071;
      const int u = r >> 13, q = r & 8191;
      const int kg = q >> 11, n = (q >> 3) & 255, j = q & 7;
      const int k = u * 32 + kg * 8 + j;
      const int g = 2 * p + (n >> 7), col = n & 127;
      v = HW1[((size_t)g * 512 + k) * 128 + col];
    } else if (idx < P_H3) {                // H2: 4 pairs x 4 units [kg4][128n][8]
      const int e = idx - P_H2;
      const int p = e >> 14, r = e & 16383;
      const int u = r >> 12, q = r & 4095;
      const int kg = q >> 10, n = (q >> 3) & 127, j = q & 7;
      const int k = u * 32 + kg * 8 + j;
      const int g = 2 * p + (n >> 6), col = n & 63;
      v = HW2[((size_t)g * 128 + k) * 64 + col];
    } else if (idx < P_H4) {                // H3: 4 pairs x 2 units [kg4][64n][8]
      const int e = idx - P_H3;
      const int p = e >> 12, r = e & 4095;
      const int u = r >> 11, q = r & 2047;
      const int kg = q >> 9, n = (q >> 3) & 63, j = q & 7;
      const int k = u * 32 + kg * 8 + j;
      const int g = 2 * p + (n >> 5), col = n & 31;
      v = HW3[((size_t)g * 64 + k) * 32 + col];
    } else {                                // H4: 4 pairs x 1 unit [kg4][32n][8]
      const int e = idx - P_H4;
      const int p = e >> 10, q = e & 1023;
      const int kg = q >> 8, n = (q >> 3) & 31, j = q & 7;
      const int k = kg * 8 + j;
      const int g = 2 * p + (n >> 4), col = n & 15;
      v = HW4[((size_t)g * 32 + k) * 16 + col];
    }
    wp[idx] = f2bf(v);
  }
}

// ---------------- fused MLP: 16 waves, barrier-free heads ----------------
__global__ __launch_bounds__(NTHREADS)
__attribute__((amdgpu_waves_per_eu(4, 4)))
void fused_mlp(const float* __restrict__ x, const u16* __restrict__ wp,
               const float* __restrict__ b1, const float* __restrict__ b2,
               const float* __restrict__ b3, const float* __restrict__ b4,
               const float* __restrict__ Hb1, const float* __restrict__ Hb2,
               const float* __restrict__ Hb3, const float* __restrict__ Hb4,
               const float* __restrict__ hw5, const float* __restrict__ Hb5,
               float* __restrict__ out)
{
  extern __shared__ char lds[];
  const int tid = threadIdx.x;
  const int lane = tid & 63;
  const int l15 = lane & 15;
  const int rgrp = lane >> 4;
  const int kg = lane >> 4;
  const int wid = tid >> 6;        // 0..15
  const int row0 = blockIdx.x * TB;
  const char* wpB = reinterpret_cast<const char*>(wp);

  // ---- phase 0: xs = [x, sin x, cos x, 0, 0] bf16, rows 128B swizzled ----
  for (int i = tid; i < TB * 10; i += NTHREADS) {
    const int r = i / 10, c = i % 10;
    const float xv = x[(size_t)(row0 + r) * 10 + c];
    const int sw = (r & 7) << 4;
    char* rowp = lds + XS_OFF + r * 128;
    *reinterpret_cast<u16*>(rowp + ((c * 2) ^ sw)) = f2bf(xv);
    *reinterpret_cast<u16*>(rowp + (((c + 10) * 2) ^ sw)) = f2bf(__sinf(xv));
    *reinterpret_cast<u16*>(rowp + (((c + 20) * 2) ^ sw)) = f2bf(__cosf(xv));
  }
  for (int i = tid; i < TB * 2; i += NTHREADS) {
    const int r = i >> 1, c = 30 + (i & 1);
    *reinterpret_cast<u16*>(lds + XS_OFF + r * 128 + ((c * 2) ^ ((r & 7) << 4))) = 0;
  }
  __syncthreads();

  // ---- L1: h = relu(xs @ W1 + b1), K=32(pad) ----
  {
    f32x4 acc[4][2];
    gemm_reg<4, 2, 1>(lds, XS_OFF, 128, 0, 0,
                      wpB + (size_t)P_L1 * 2, 32768, 512, wid * 32, kg, l15, acc);
    epi_bb(lds, acc, b1, 512, true, false, wid, l15, rgrp);  // h vs xs disjoint
    __syncthreads();
  }
  // ---- L2: relu, L3: relu+concat, L4: no relu ----
  {
    f32x4 acc[4][2];
    gemm_reg<4, 2, 16>(lds, H_OFF, 1024, 0, 0,
                       wpB + (size_t)P_L2 * 2, 32768, 512, wid * 32, kg, l15, acc);
    __syncthreads();
    epi_bb(lds, acc, b2, 512, true, false, wid, l15, rgrp);
    __syncthreads();
  }
  {
    f32x4 acc[4][2];
    gemm_reg<4, 2, 16>(lds, H_OFF, 1024, 0, 0,
                       wpB + (size_t)P_L3 * 2, 32768, 512, wid * 32, kg, l15, acc);
    __syncthreads();
    epi_bb(lds, acc, b3, 482, true, true, wid, l15, rgrp);
    __syncthreads();
  }
  {
    f32x4 acc[4][2];
    gemm_reg<4, 2, 16>(lds, H_OFF, 1024, 0, 0,
                       wpB + (size_t)P_L4 * 2, 32768, 512, wid * 32, kg, l15, acc);
    __syncthreads();
    epi_bb(lds, acc, b4, 512, false, false, wid, l15, rgrp);
    __syncthreads();
  }

  // ---- H1 for all 4 pairs: y1[p] = relu(h @ HW1[pair p] + Hb1) ----
  for (int p = 0; p < 4; ++p) {
    f32x4 acc[4][1];
    gemm_reg<4, 1, 16>(lds, H_OFF, 1024, 0, 0,
                       wpB + (size_t)P_H1 * 2 + (size_t)p * 262144, 16384, 256,
                       wid * 16, kg, l15, acc);
    if (p == 3) __syncthreads();           // all h reads done before overwrite
    const int y1b = (p == 3) ? 32768 : 65536 + p * 32768;
    const int gc = wid * 16 + l15;         // 0..255
    const float bv = Hb1[(2 * p + (gc >> 7)) * 128 + (gc & 127)];
#pragma unroll
    for (int fi = 0; fi < 4; ++fi)
#pragma unroll
      for (int r = 0; r < 4; ++r) {
        const int m = fi * 16 + rgrp * 4 + r;
        const float v = fmaxf(acc[fi][0][r] + bv, 0.f);
        *reinterpret_cast<u16*>(lds + y1b + m * 512 + ((gc * 2) ^ ((m & 7) << 4))) = f2bf(v);
      }
  }
  __syncthreads();                         // y1 (all pairs) visible

  // ---- H2..H5: fully wave-private, zero barriers ----
  {
    const int g = wid >> 1, half = wid & 1, pair = g >> 1, side = g & 1;
    const int y1b = (pair == 3) ? 32768 : 65536 + pair * 32768;
    const int aBase = y1b + half * 16384;          // rows half*32.., stride 512B
    const int scrOff = aBase + side * 256;         // wave-private scratch slice
    char* scr = lds + scrOff;

    // H2: y2[32r][64c] = relu(y1[rows][side cols] @ HW2[g] + Hb2[g]), K=128
    {
      f32x4 a2[2][4];
      gemm_reg<2, 4, 4>(lds, aBase, 512, side * 128, 0,
                        wpB + (size_t)P_H2 * 2 + (size_t)pair * 32768, 8192, 128,
                        side * 64, kg, l15, a2);
#pragma unroll
      for (int fj = 0; fj < 4; ++fj) {
        const int c = fj * 16 + l15;
        const float bv = Hb2[g * 64 + c];
#pragma unroll
        for (int fi = 0; fi < 2; ++fi)
#pragma unroll
          for (int r = 0; r < 4; ++r) {
            const int rl = fi * 16 + rgrp * 4 + r;
            const float v = fmaxf(a2[fi][fj][r] + bv, 0.f);
            *reinterpret_cast<u16*>(scr + rl * 512 + ((c * 2) ^ ((rl & 7) << 4))) = f2bf(v);
          }
      }
    }
    // H3: y3[32r][32c] = relu(y2 @ HW3[g] + Hb3[g]), K=64
    {
      f32x4 a3[2][2];
      gemm_reg<2, 2, 2>(lds, scrOff, 512, 0, 0,
                        wpB + (size_t)P_H3 * 2 + (size_t)pair * 8192, 4096, 64,
                        side * 32, kg, l15, a3);
#pragma unroll
      for (int fj = 0; fj < 2; ++fj) {
        const int c = fj * 16 + l15;
        const float bv = Hb3[g * 32 + c];
#pragma unroll
        for (int fi = 0; fi < 2; ++fi)
#pragma unroll
          for (int r = 0; r < 4; ++r) {
            const int rl = fi * 16 + rgrp * 4 + r;
            const float v = fmaxf(a3[fi][fj][r] + bv, 0.f);
            *reinterpret_cast<u16*>(scr + rl * 512 + ((c * 2) ^ ((rl & 7) << 4))) = f2bf(v);
          }
      }
    }
    // H4: y4[32r][16c] = relu(y3 @ HW4[g] + Hb4[g]), K=32
    {
      f32x4 a4[2][1];
      gemm_reg<2, 1, 1>(lds, scrOff, 512, 0, 0,
                        wpB + (size_t)P_H4 * 2 + (size_t)pair * 2048, 2048, 32,
                        side * 16, kg, l15, a4);
      const int c = l15;
      const float bv = Hb4[g * 16 + c];
#pragma unroll
      for (int fi = 0; fi < 2; ++fi)
#pragma unroll
        for (int r = 0; r < 4; ++r) {
          const int rl = fi * 16 + rgrp * 4 + r;
          const float v = fmaxf(a4[fi][0][r] + bv, 0.f);
          *reinterpret_cast<u16*>(scr + rl * 512 + ((c * 2) ^ ((rl & 7) << 4))) = f2bf(v);
        }
    }
    // H5: out[row][g] = y4 @ HW5[g] + Hb5[g]  (two 8-wide lane partials)
    {
      const int r = lane & 31, kh = lane >> 5;
      const s16x8 y4v = *reinterpret_cast<const s16x8*>(
          scr + r * 512 + ((kh * 16) ^ ((r & 7) << 4)));
      float partial = 0.f;
#pragma unroll
      for (int j = 0; j < 8; ++j)
        partial += bf2f((u16)y4v[j]) * hw5[g * 16 + kh * 8 + j];
      partial += __shfl_xor(partial, 32, 64);
      if (kh == 0)
        out[(size_t)(row0 + half * 32 + r) * 8 + g] = Hb5[g] + partial;
    }
  }
}

extern "C" void kernel_launch(void* const* d_in, const int* in_sizes, int n_in,
                              void* d_out, int out_size, void* d_ws, size_t ws_size,
                              hipStream_t stream) {
  (void)in_sizes; (void)n_in; (void)out_size; (void)ws_size;
  const float* x   = (const float*)d_in[0];
  const float* W1  = (const float*)d_in[1];
  const float* b1  = (const float*)d_in[2];
  const float* W2  = (const float*)d_in[3];
  const float* b2  = (const float*)d_in[4];
  const float* W3  = (const float*)d_in[5];
  const float* b3  = (const float*)d_in[6];
  const float* W4  = (const float*)d_in[7];
  const float* b4  = (const float*)d_in[8];
  const float* HW1 = (const float*)d_in[9];
  const float* Hb1 = (const float*)d_in[10];
  const float* HW2 = (const float*)d_in[11];
  const float* Hb2 = (const float*)d_in[12];
  const float* HW3 = (const float*)d_in[13];
  const float* Hb3 = (const float*)d_in[14];
  const float* HW4 = (const float*)d_in[15];
  const float* Hb4 = (const float*)d_in[16];
  const float* HW5 = (const float*)d_in[17];
  const float* Hb5 = (const float*)d_in[18];
  float* out = (float*)d_out;
  u16* wp = (u16*)d_ws;

  prep_weights<<<2048, 256, 0, stream>>>(W1, W2, W3, W4, HW1, HW2, HW3, HW4, wp);

  hipFuncSetAttribute((const void*)fused_mlp,
                      hipFuncAttributeMaxDynamicSharedMemorySize, LDS_BYTES);
  fused_mlp<<<131072 / TB, NTHREADS, LDS_BYTES, stream>>>(
      x, wp, b1, b2, b3, b4, Hb1, Hb2, Hb3, Hb4, HW5, Hb5, out);
}

// Round 12
// 427.654 us; speedup vs baseline: 1.6356x; 1.6356x over previous
//
#include <hip/hip_runtime.h>
#include <hip/hip_bf16.h>

typedef short s16x8 __attribute__((ext_vector_type(8)));
typedef float f32x4 __attribute__((ext_vector_type(4)));
typedef unsigned short u16;
typedef unsigned int u32;

#define TB 64
#define NTHREADS 512

// prep-buffer element offsets (bf16 elements)
#define P_L1 0
#define P_L2 16384
#define P_L3 278528
#define P_L4 540672
#define P_H1 802816
#define P_H2 1327104
#define P_H3 1392640
#define P_H4 1409024
#define P_TOT 1413120

// LDS byte offsets
// h  [64][1024B] at 0..64K, swz (m&7)<<4
// xs [64][128B]  at 64K..72K
// y1 head slices: 4 x [64][256B] at 72K..136K; wave (g,half) owns rows
//   half*32..half*32+31 of slice (g&3) through the whole head chain
//   (H2/H3/H4 scratch written in-place into the wave's own 32 rows).
#define H_OFF   0
#define XS_OFF  65536
#define Y1_OFF  73728
#define LDS_BYTES 139264  // 136 KB

__device__ __forceinline__ u16 f2bf(float v) {
  __hip_bfloat16 b = __float2bfloat16(v);
  return __builtin_bit_cast(u16, b);
}
__device__ __forceinline__ float bf2f(u16 u) {
  u32 x = ((u32)u) << 16;
  return __builtin_bit_cast(float, x);
}

// load one wave's B fragments for a K32 unit straight into registers
template<int FN>
__device__ __forceinline__ void loadB(s16x8 (&b)[FN], const char* unit,
                                      int nCols, int bColBase, int kg, int l15) {
#pragma unroll
  for (int fj = 0; fj < FN; ++fj) {
    const int n = bColBase + fj * 16 + l15;
    b[fj] = *reinterpret_cast<const s16x8*>(unit + (kg * nCols + n) * 16);
  }
}

// one K32 step: read A frags from LDS, FM*FN MFMAs with B regs
template<int FM, int FN>
__device__ __forceinline__ void mfma_step(
    const char* lds, int aOff, int aRB, int kByte, int mBase, int l15,
    const s16x8 (&b)[FN], f32x4 (&acc)[FM][FN]) {
  s16x8 a[FM];
#pragma unroll
  for (int fi = 0; fi < FM; ++fi) {
    const int m = mBase + fi * 16 + l15;
    a[fi] = *reinterpret_cast<const s16x8*>(
        lds + aOff + m * aRB + (kByte ^ (((m & 7) << 4) & (aRB - 1))));
  }
#pragma unroll
  for (int fi = 0; fi < FM; ++fi)
#pragma unroll
    for (int fj = 0; fj < FN; ++fj)
      acc[fi][fj] = __builtin_amdgcn_mfma_f32_16x16x32_bf16(a[fi], b[fj], acc[fi][fj], 0, 0, 0);
}

// barrier-free K-loop GEMM: A from LDS, B global->regs (named 2-deep dbuf)
template<int FM, int FN, int KSTEPS>
__device__ __forceinline__ void gemm_reg(
    const char* lds, int aOff, int aRB, int aColBase, int mBase,
    const char* bGlob, int unitStride, int nCols, int bColBase,
    int kg, int l15, f32x4 (&acc)[FM][FN]) {
#pragma unroll
  for (int i = 0; i < FM; ++i)
#pragma unroll
    for (int j = 0; j < FN; ++j) { f32x4 z = {0.f,0.f,0.f,0.f}; acc[i][j] = z; }
  s16x8 bA[FN], bB[FN];
  loadB<FN>(bA, bGlob, nCols, bColBase, kg, l15);
#pragma unroll
  for (int ks = 0; ks < KSTEPS; ks += 2) {
    if (ks + 1 < KSTEPS)
      loadB<FN>(bB, bGlob + (size_t)(ks + 1) * unitStride, nCols, bColBase, kg, l15);
    mfma_step<FM, FN>(lds, aOff, aRB, (aColBase + ks * 32 + kg * 8) * 2,
                      mBase, l15, bA, acc);
    if (ks + 1 < KSTEPS) {
      if (ks + 2 < KSTEPS)
        loadB<FN>(bA, bGlob + (size_t)(ks + 2) * unitStride, nCols, bColBase, kg, l15);
      mfma_step<FM, FN>(lds, aOff, aRB, (aColBase + (ks + 1) * 32 + kg * 8) * 2,
                        mBase, l15, bB, acc);
    }
  }
}

// backbone epilogue: bias (+relu) (+concat relu(xs) cols>=482) -> bf16 -> h
__device__ __forceinline__ void epi_bb(char* lds, const f32x4 (&acc)[4][4],
    const float* bias, int biasLim, bool relu, bool concatXS, int tid)
{
  const int lane = tid & 63;
  const int l15 = lane & 15, rgrp = lane >> 4;
  const int wid = tid >> 6;
#pragma unroll
  for (int fj = 0; fj < 4; ++fj) {
    const int gc = wid * 64 + fj * 16 + l15;
    const float bv = (gc < biasLim) ? bias[gc] : 0.f;
#pragma unroll
    for (int fi = 0; fi < 4; ++fi) {
#pragma unroll
      for (int r = 0; r < 4; ++r) {
        const int m = fi * 16 + rgrp * 4 + r;
        float v = acc[fi][fj][r] + bv;
        if (relu) v = fmaxf(v, 0.f);
        u16 hv = f2bf(v);
        if (concatXS && gc >= 482) {
          const int c2 = gc - 482;
          const float xv = bf2f(*reinterpret_cast<const u16*>(
              lds + XS_OFF + m * 128 + ((c2 * 2) ^ ((m & 7) << 4))));
          hv = f2bf(fmaxf(xv, 0.f));
        }
        *reinterpret_cast<u16*>(lds + H_OFF + m * 1024 + ((gc * 2) ^ ((m & 7) << 4))) = hv;
      }
    }
  }
}

// ---------------- weight prep: fp32 -> bf16 [kg][n][8j] packets ----------------
__global__ __launch_bounds__(256)
void prep_weights(const float* __restrict__ W1, const float* __restrict__ W2,
                  const float* __restrict__ W3, const float* __restrict__ W4,
                  const float* __restrict__ HW1, const float* __restrict__ HW2,
                  const float* __restrict__ HW3, const float* __restrict__ HW4,
                  u16* __restrict__ wp)
{
  for (int idx = blockIdx.x * blockDim.x + threadIdx.x; idx < P_TOT;
       idx += gridDim.x * blockDim.x) {
    float v;
    if (idx < P_L2) {                       // L1: 1 unit [kg4][512n][8], K pad 30->32
      const int e = idx;
      const int kg = e >> 12, n = (e >> 3) & 511, j = e & 7;
      const int k = kg * 8 + j;
      v = (k < 30) ? W1[k * 512 + n] : 0.f;
    } else if (idx < P_L3) {                // L2: 16 units of 16384 elems
      const int e = idx - P_L2;
      const int u = e >> 14, r = e & 16383;
      const int kg = r >> 12, n = (r >> 3) & 511, j = r & 7;
      const int k = u * 32 + kg * 8 + j;
      v = W2[k * 512 + n];
    } else if (idx < P_L4) {                // L3 (cols >= 482 zero)
      const int e = idx - P_L3;
      const int u = e >> 14, r = e & 16383;
      const int kg = r >> 12, n = (r >> 3) & 511, j = r & 7;
      const int k = u * 32 + kg * 8 + j;
      v = (n < 482) ? W3[k * 482 + n] : 0.f;
    } else if (idx < P_H1) {                // L4
      const int e = idx - P_L4;
      const int u = e >> 14, r = e & 16383;
      const int kg = r >> 12, n = (r >> 3) & 511, j = r & 7;
      const int k = u * 32 + kg * 8 + j;
      v = W4[k * 512 + n];
    } else if (idx < P_H2) {                // H1: 4 pairs x 16 units [kg4][256n][8]
      const int e = idx - P_H1;
      const int p = e >> 17, r = e & 131071;
      const int u = r >> 13, q = r & 8191;
      const int kg = q >> 11, n = (q >> 3) & 255, j = q & 7;
      const int k = u * 32 + kg * 8 + j;
      const int g = 2 * p + (n >> 7), col = n & 127;
      v = HW1[((size_t)g * 512 + k) * 128 + col];
    } else if (idx < P_H3) {                // H2: 4 pairs x 4 units [kg4][128n][8]
      const int e = idx - P_H2;
      const int p = e >> 14, r = e & 16383;
      const int u = r >> 12, q = r & 4095;
      const int kg = q >> 10, n = (q >> 3) & 127, j = q & 7;
      const int k = u * 32 + kg * 8 + j;
      const int g = 2 * p + (n >> 6), col = n & 63;
      v = HW2[((size_t)g * 128 + k) * 64 + col];
    } else if (idx < P_H4) {                // H3: 4 pairs x 2 units [kg4][64n][8]
      const int e = idx - P_H3;
      const int p = e >> 12, r = e & 4095;
      const int u = r >> 11, q = r & 2047;
      const int kg = q >> 9, n = (q >> 3) & 63, j = q & 7;
      const int k = u * 32 + kg * 8 + j;
      const int g = 2 * p + (n >> 5), col = n & 31;
      v = HW3[((size_t)g * 64 + k) * 32 + col];
    } else {                                // H4: 4 pairs x 1 unit [kg4][32n][8]
      const int e = idx - P_H4;
      const int p = e >> 10, q = e & 1023;
      const int kg = q >> 8, n = (q >> 3) & 31, j = q & 7;
      const int k = kg * 8 + j;
      const int g = 2 * p + (n >> 4), col = n & 15;
      v = HW4[((size_t)g * 32 + k) * 16 + col];
    }
    wp[idx] = f2bf(v);
  }
}

// ---------------- fused MLP: 8 waves (R5 shape), wave-private heads ----------------
__global__ __launch_bounds__(NTHREADS, 2)
void fused_mlp(const float* __restrict__ x, const u16* __restrict__ wp,
               const float* __restrict__ b1, const float* __restrict__ b2,
               const float* __restrict__ b3, const float* __restrict__ b4,
               const float* __restrict__ Hb1, const float* __restrict__ Hb2,
               const float* __restrict__ Hb3, const float* __restrict__ Hb4,
               const float* __restrict__ hw5, const float* __restrict__ Hb5,
               float* __restrict__ out)
{
  extern __shared__ char lds[];
  const int tid = threadIdx.x;
  const int lane = tid & 63;
  const int l15 = lane & 15;
  const int rgrp = lane >> 4;
  const int kg = lane >> 4;
  const int wid = tid >> 6;        // 0..7
  const int row0 = blockIdx.x * TB;
  const char* wpB = reinterpret_cast<const char*>(wp);

  // ---- phase 0: xs = [x, sin x, cos x, 0, 0] bf16, rows 128B swizzled ----
  for (int i = tid; i < TB * 10; i += NTHREADS) {
    const int r = i / 10, c = i % 10;
    const float xv = x[(size_t)(row0 + r) * 10 + c];
    const int sw = (r & 7) << 4;
    char* rowp = lds + XS_OFF + r * 128;
    *reinterpret_cast<u16*>(rowp + ((c * 2) ^ sw)) = f2bf(xv);
    *reinterpret_cast<u16*>(rowp + (((c + 10) * 2) ^ sw)) = f2bf(__sinf(xv));
    *reinterpret_cast<u16*>(rowp + (((c + 20) * 2) ^ sw)) = f2bf(__cosf(xv));
  }
  for (int i = tid; i < TB * 2; i += NTHREADS) {
    const int r = i >> 1, c = 30 + (i & 1);
    *reinterpret_cast<u16*>(lds + XS_OFF + r * 128 + ((c * 2) ^ ((r & 7) << 4))) = 0;
  }
  __syncthreads();

  // ---- L1: h = relu(xs @ W1 + b1), K=32(pad) ----
  {
    f32x4 acc[4][4];
    gemm_reg<4, 4, 1>(lds, XS_OFF, 128, 0, 0,
                      wpB + (size_t)P_L1 * 2, 8192, 512, wid * 64, kg, l15, acc);
    epi_bb(lds, acc, b1, 512, true, false, tid);   // h-write vs xs-read disjoint
    __syncthreads();
  }
  // ---- L2: relu, L3: relu+concat, L4: no relu ----
  {
    f32x4 acc[4][4];
    gemm_reg<4, 4, 16>(lds, H_OFF, 1024, 0, 0,
                       wpB + (size_t)P_L2 * 2, 32768, 512, wid * 64, kg, l15, acc);
    __syncthreads();
    epi_bb(lds, acc, b2, 512, true, false, tid);
    __syncthreads();
  }
  {
    f32x4 acc[4][4];
    gemm_reg<4, 4, 16>(lds, H_OFF, 1024, 0, 0,
                       wpB + (size_t)P_L3 * 2, 32768, 512, wid * 64, kg, l15, acc);
    __syncthreads();
    epi_bb(lds, acc, b3, 482, true, true, tid);
    __syncthreads();
  }
  {
    f32x4 acc[4][4];
    gemm_reg<4, 4, 16>(lds, H_OFF, 1024, 0, 0,
                       wpB + (size_t)P_L4 * 2, 32768, 512, wid * 64, kg, l15, acc);
    __syncthreads();
    epi_bb(lds, acc, b4, 512, false, false, tid);
    __syncthreads();
  }

  // ---- heads: wave = (head g, row-half); ZERO barriers from here on.
  // h is read-only; each wave owns 32 rows of one head slice end-to-end.
  {
    const int half = wid & 1;
    const int mB = half * 32;
    for (int grp = 0; grp < 2; ++grp) {
      const int g = grp * 4 + (wid >> 1);
      const int pair = g >> 1, side = g & 1;
      const int y1o = Y1_OFF + (g & 3) * 16384;   // head slice [64][256B]
      const int scrOff = y1o + half * 8192;       // this wave's 32 rows
      char* scr = lds + scrOff;

      // H1: y1[g][mB..mB+31][0..127] = relu(h @ HW1[g] + Hb1[g]), K=512
#pragma unroll
      for (int pass = 0; pass < 2; ++pass) {
        f32x4 acc[2][4];
        gemm_reg<2, 4, 16>(lds, H_OFF, 1024, 0, mB,
                           wpB + (size_t)P_H1 * 2 + (size_t)pair * 262144, 16384, 256,
                           side * 128 + pass * 64, kg, l15, acc);
#pragma unroll
        for (int fj = 0; fj < 4; ++fj) {
          const int c = pass * 64 + fj * 16 + l15;          // 0..127
          const float bv = Hb1[g * 128 + c];
#pragma unroll
          for (int fi = 0; fi < 2; ++fi)
#pragma unroll
            for (int r = 0; r < 4; ++r) {
              const int m = mB + fi * 16 + rgrp * 4 + r;    // global row in slice
              const float v = fmaxf(acc[fi][fj][r] + bv, 0.f);
              *reinterpret_cast<u16*>(lds + y1o + m * 256 + ((c * 2) ^ ((m & 7) << 4))) = f2bf(v);
            }
        }
      }
      // H2: y2[32][64] = relu(y1_own_rows @ HW2[g] + Hb2[g]), K=128
      {
        f32x4 a2[2][4];
        gemm_reg<2, 4, 4>(lds, scrOff, 256, 0, 0,
                          wpB + (size_t)P_H2 * 2 + (size_t)pair * 32768, 8192, 128,
                          side * 64, kg, l15, a2);
#pragma unroll
        for (int fj = 0; fj < 4; ++fj) {
          const int c = fj * 16 + l15;
          const float bv = Hb2[g * 64 + c];
#pragma unroll
          for (int fi = 0; fi < 2; ++fi)
#pragma unroll
            for (int r = 0; r < 4; ++r) {
              const int rl = fi * 16 + rgrp * 4 + r;
              const float v = fmaxf(a2[fi][fj][r] + bv, 0.f);
              *reinterpret_cast<u16*>(scr + rl * 256 + ((c * 2) ^ ((rl & 7) << 4))) = f2bf(v);
            }
        }
      }
      // H3: y3[32][32] = relu(y2 @ HW3[g] + Hb3[g]), K=64
      {
        f32x4 a3[2][2];
        gemm_reg<2, 2, 2>(lds, scrOff, 256, 0, 0,
                          wpB + (size_t)P_H3 * 2 + (size_t)pair * 8192, 4096, 64,
                          side * 32, kg, l15, a3);
#pragma unroll
        for (int fj = 0; fj < 2; ++fj) {
          const int c = fj * 16 + l15;
          const float bv = Hb3[g * 32 + c];
#pragma unroll
          for (int fi = 0; fi < 2; ++fi)
#pragma unroll
            for (int r = 0; r < 4; ++r) {
              const int rl = fi * 16 + rgrp * 4 + r;
              const float v = fmaxf(a3[fi][fj][r] + bv, 0.f);
              *reinterpret_cast<u16*>(scr + rl * 256 + ((c * 2) ^ ((rl & 7) << 4))) = f2bf(v);
            }
        }
      }
      // H4: y4[32][16] = relu(y3 @ HW4[g] + Hb4[g]), K=32
      {
        f32x4 a4[2][1];
        gemm_reg<2, 1, 1>(lds, scrOff, 256, 0, 0,
                          wpB + (size_t)P_H4 * 2 + (size_t)pair * 2048, 2048, 32,
                          side * 16, kg, l15, a4);
        const int c = l15;
        const float bv = Hb4[g * 16 + c];
#pragma unroll
        for (int fi = 0; fi < 2; ++fi)
#pragma unroll
          for (int r = 0; r < 4; ++r) {
            const int rl = fi * 16 + rgrp * 4 + r;
            const float v = fmaxf(a4[fi][0][r] + bv, 0.f);
            *reinterpret_cast<u16*>(scr + rl * 256 + ((c * 2) ^ ((rl & 7) << 4))) = f2bf(v);
          }
      }
      // H5: out[row][g] = y4 @ HW5[g] + Hb5[g]  (two 8-wide lane partials)
      {
        const int r = lane & 31, kh = lane >> 5;
        const s16x8 y4v = *reinterpret_cast<const s16x8*>(
            scr + r * 256 + ((kh * 16) ^ ((r & 7) << 4)));
        float partial = 0.f;
#pragma unroll
        for (int j = 0; j < 8; ++j)
          partial += bf2f((u16)y4v[j]) * hw5[g * 16 + kh * 8 + j];
        partial += __shfl_xor(partial, 32, 64);
        if (kh == 0)
          out[(size_t)(row0 + mB + r) * 8 + g] = Hb5[g] + partial;
      }
    }
  }
}

extern "C" void kernel_launch(void* const* d_in, const int* in_sizes, int n_in,
                              void* d_out, int out_size, void* d_ws, size_t ws_size,
                              hipStream_t stream) {
  (void)in_sizes; (void)n_in; (void)out_size; (void)ws_size;
  const float* x   = (const float*)d_in[0];
  const float* W1  = (const float*)d_in[1];
  const float* b1  = (const float*)d_in[2];
  const float* W2  = (const float*)d_in[3];
  const float* b2  = (const float*)d_in[4];
  const float* W3  = (const float*)d_in[5];
  const float* b3  = (const float*)d_in[6];
  const float* W4  = (const float*)d_in[7];
  const float* b4  = (const float*)d_in[8];
  const float* HW1 = (const float*)d_in[9];
  const float* Hb1 = (const float*)d_in[10];
  const float* HW2 = (const float*)d_in[11];
  const float* Hb2 = (const float*)d_in[12];
  const float* HW3 = (const float*)d_in[13];
  const float* Hb3 = (const float*)d_in[14];
  const float* HW4 = (const float*)d_in[15];
  const float* Hb4 = (const float*)d_in[16];
  const float* HW5 = (const float*)d_in[17];
  const float* Hb5 = (const float*)d_in[18];
  float* out = (float*)d_out;
  u16* wp = (u16*)d_ws;

  prep_weights<<<2048, 256, 0, stream>>>(W1, W2, W3, W4, HW1, HW2, HW3, HW4, wp);

  hipFuncSetAttribute((const void*)fused_mlp,
                      hipFuncAttributeMaxDynamicSharedMemorySize, LDS_BYTES);
  fused_mlp<<<131072 / TB, NTHREADS, LDS_BYTES, stream>>>(
      x, wp, b1, b2, b3, b4, Hb1, Hb2, Hb3, Hb4, HW5, Hb5, out);
}

// Round 13
// 395.645 us; speedup vs baseline: 1.7680x; 1.0809x over previous
//
#include <hip/hip_runtime.h>
#include <hip/hip_bf16.h>

typedef short s16x8 __attribute__((ext_vector_type(8)));
typedef float f32x4 __attribute__((ext_vector_type(4)));
typedef unsigned short u16;
typedef unsigned int u32;

#define TB 64
#define NTHREADS 512

// prep-buffer element offsets (bf16 elements)
#define P_L1 0
#define P_L2 16384
#define P_L3 278528
#define P_L4 540672
#define P_H1 802816
#define P_H2 1327104
#define P_H3 1392640
#define P_H4 1409024
#define P_TOT 1413120

// LDS byte offsets
// h  [64][1024B] at 0..64K, swz (m&7)<<4
// xs [64][128B]  at 64K..72K
// y1 head slices: 4 x [64][256B] at 72K..136K (slice g&3, reused across grps)
// H1: wave (head, colhalf) writes all 64 rows x 64 cols  (B read-once)
// H2+: wave (head, rowhalf) owns rows half*32..+31 in-place (R12 scheme)
#define H_OFF   0
#define XS_OFF  65536
#define Y1_OFF  73728
#define LDS_BYTES 139264  // 136 KB

__device__ __forceinline__ u16 f2bf(float v) {
  __hip_bfloat16 b = __float2bfloat16(v);
  return __builtin_bit_cast(u16, b);
}
__device__ __forceinline__ float bf2f(u16 u) {
  u32 x = ((u32)u) << 16;
  return __builtin_bit_cast(float, x);
}

// load one wave's B fragments for a K32 unit straight into registers
template<int FN>
__device__ __forceinline__ void loadB(s16x8 (&b)[FN], const char* unit,
                                      int nCols, int bColBase, int kg, int l15) {
#pragma unroll
  for (int fj = 0; fj < FN; ++fj) {
    const int n = bColBase + fj * 16 + l15;
    b[fj] = *reinterpret_cast<const s16x8*>(unit + (kg * nCols + n) * 16);
  }
}

// one K32 step: read A frags from LDS, FM*FN MFMAs with B regs
template<int FM, int FN>
__device__ __forceinline__ void mfma_step(
    const char* lds, int aOff, int aRB, int kByte, int mBase, int l15,
    const s16x8 (&b)[FN], f32x4 (&acc)[FM][FN]) {
  s16x8 a[FM];
#pragma unroll
  for (int fi = 0; fi < FM; ++fi) {
    const int m = mBase + fi * 16 + l15;
    a[fi] = *reinterpret_cast<const s16x8*>(
        lds + aOff + m * aRB + (kByte ^ (((m & 7) << 4) & (aRB - 1))));
  }
#pragma unroll
  for (int fi = 0; fi < FM; ++fi)
#pragma unroll
    for (int fj = 0; fj < FN; ++fj)
      acc[fi][fj] = __builtin_amdgcn_mfma_f32_16x16x32_bf16(a[fi], b[fj], acc[fi][fj], 0, 0, 0);
}

// barrier-free K-loop GEMM: A from LDS, B global->regs (named 2-deep dbuf)
template<int FM, int FN, int KSTEPS>
__device__ __forceinline__ void gemm_reg(
    const char* lds, int aOff, int aRB, int aColBase, int mBase,
    const char* bGlob, int unitStride, int nCols, int bColBase,
    int kg, int l15, f32x4 (&acc)[FM][FN]) {
#pragma unroll
  for (int i = 0; i < FM; ++i)
#pragma unroll
    for (int j = 0; j < FN; ++j) { f32x4 z = {0.f,0.f,0.f,0.f}; acc[i][j] = z; }
  s16x8 bA[FN], bB[FN];
  loadB<FN>(bA, bGlob, nCols, bColBase, kg, l15);
#pragma unroll
  for (int ks = 0; ks < KSTEPS; ks += 2) {
    if (ks + 1 < KSTEPS)
      loadB<FN>(bB, bGlob + (size_t)(ks + 1) * unitStride, nCols, bColBase, kg, l15);
    mfma_step<FM, FN>(lds, aOff, aRB, (aColBase + ks * 32 + kg * 8) * 2,
                      mBase, l15, bA, acc);
    if (ks + 1 < KSTEPS) {
      if (ks + 2 < KSTEPS)
        loadB<FN>(bA, bGlob + (size_t)(ks + 2) * unitStride, nCols, bColBase, kg, l15);
      mfma_step<FM, FN>(lds, aOff, aRB, (aColBase + (ks + 1) * 32 + kg * 8) * 2,
                        mBase, l15, bB, acc);
    }
  }
}

// backbone epilogue: bias (+relu) (+concat relu(xs) cols>=482) -> bf16 -> h
__device__ __forceinline__ void epi_bb(char* lds, const f32x4 (&acc)[4][4],
    const float* bias, int biasLim, bool relu, bool concatXS, int tid)
{
  const int lane = tid & 63;
  const int l15 = lane & 15, rgrp = lane >> 4;
  const int wid = tid >> 6;
#pragma unroll
  for (int fj = 0; fj < 4; ++fj) {
    const int gc = wid * 64 + fj * 16 + l15;
    const float bv = (gc < biasLim) ? bias[gc] : 0.f;
#pragma unroll
    for (int fi = 0; fi < 4; ++fi) {
#pragma unroll
      for (int r = 0; r < 4; ++r) {
        const int m = fi * 16 + rgrp * 4 + r;
        float v = acc[fi][fj][r] + bv;
        if (relu) v = fmaxf(v, 0.f);
        u16 hv = f2bf(v);
        if (concatXS && gc >= 482) {
          const int c2 = gc - 482;
          const float xv = bf2f(*reinterpret_cast<const u16*>(
              lds + XS_OFF + m * 128 + ((c2 * 2) ^ ((m & 7) << 4))));
          hv = f2bf(fmaxf(xv, 0.f));
        }
        *reinterpret_cast<u16*>(lds + H_OFF + m * 1024 + ((gc * 2) ^ ((m & 7) << 4))) = hv;
      }
    }
  }
}

// ---------------- weight prep: fp32 -> bf16 [kg][n][8j] packets ----------------
__global__ __launch_bounds__(256)
void prep_weights(const float* __restrict__ W1, const float* __restrict__ W2,
                  const float* __restrict__ W3, const float* __restrict__ W4,
                  const float* __restrict__ HW1, const float* __restrict__ HW2,
                  const float* __restrict__ HW3, const float* __restrict__ HW4,
                  u16* __restrict__ wp)
{
  for (int idx = blockIdx.x * blockDim.x + threadIdx.x; idx < P_TOT;
       idx += gridDim.x * blockDim.x) {
    float v;
    if (idx < P_L2) {                       // L1: 1 unit [kg4][512n][8], K pad 30->32
      const int e = idx;
      const int kg = e >> 12, n = (e >> 3) & 511, j = e & 7;
      const int k = kg * 8 + j;
      v = (k < 30) ? W1[k * 512 + n] : 0.f;
    } else if (idx < P_L3) {                // L2: 16 units of 16384 elems
      const int e = idx - P_L2;
      const int u = e >> 14, r = e & 16383;
      const int kg = r >> 12, n = (r >> 3) & 511, j = r & 7;
      const int k = u * 32 + kg * 8 + j;
      v = W2[k * 512 + n];
    } else if (idx < P_L4) {                // L3 (cols >= 482 zero)
      const int e = idx - P_L3;
      const int u = e >> 14, r = e & 16383;
      const int kg = r >> 12, n = (r >> 3) & 511, j = r & 7;
      const int k = u * 32 + kg * 8 + j;
      v = (n < 482) ? W3[k * 482 + n] : 0.f;
    } else if (idx < P_H1) {                // L4
      const int e = idx - P_L4;
      const int u = e >> 14, r = e & 16383;
      const int kg = r >> 12, n = (r >> 3) & 511, j = r & 7;
      const int k = u * 32 + kg * 8 + j;
      v = W4[k * 512 + n];
    } else if (idx < P_H2) {                // H1: 4 pairs x 16 units [kg4][256n][8]
      const int e = idx - P_H1;
      const int p = e >> 17, r = e & 131071;
      const int u = r >> 13, q = r & 8191;
      const int kg = q >> 11, n = (q >> 3) & 255, j = q & 7;
      const int k = u * 32 + kg * 8 + j;
      const int g = 2 * p + (n >> 7), col = n & 127;
      v = HW1[((size_t)g * 512 + k) * 128 + col];
    } else if (idx < P_H3) {                // H2: 4 pairs x 4 units [kg4][128n][8]
      const int e = idx - P_H2;
      const int p = e >> 14, r = e & 16383;
      const int u = r >> 12, q = r & 4095;
      const int kg = q >> 10, n = (q >> 3) & 127, j = q & 7;
      const int k = u * 32 + kg * 8 + j;
      const int g = 2 * p + (n >> 6), col = n & 63;
      v = HW2[((size_t)g * 128 + k) * 64 + col];
    } else if (idx < P_H4) {                // H3: 4 pairs x 2 units [kg4][64n][8]
      const int e = idx - P_H3;
      const int p = e >> 12, r = e & 4095;
      const int u = r >> 11, q = r & 2047;
      const int kg = q >> 9, n = (q >> 3) & 63, j = q & 7;
      const int k = u * 32 + kg * 8 + j;
      const int g = 2 * p + (n >> 5), col = n & 31;
      v = HW3[((size_t)g * 64 + k) * 32 + col];
    } else {                                // H4: 4 pairs x 1 unit [kg4][32n][8]
      const int e = idx - P_H4;
      const int p = e >> 10, q = e & 1023;
      const int kg = q >> 8, n = (q >> 3) & 31, j = q & 7;
      const int k = kg * 8 + j;
      const int g = 2 * p + (n >> 4), col = n & 15;
      v = HW4[((size_t)g * 32 + k) * 16 + col];
    }
    wp[idx] = f2bf(v);
  }
}

// ---------------- fused MLP: 8 waves, col-split H1, wave-private H2+ ----------------
__global__ __launch_bounds__(NTHREADS, 2)
void fused_mlp(const float* __restrict__ x, const u16* __restrict__ wp,
               const float* __restrict__ b1, const float* __restrict__ b2,
               const float* __restrict__ b3, const float* __restrict__ b4,
               const float* __restrict__ Hb1, const float* __restrict__ Hb2,
               const float* __restrict__ Hb3, const float* __restrict__ Hb4,
               const float* __restrict__ hw5, const float* __restrict__ Hb5,
               float* __restrict__ out)
{
  extern __shared__ char lds[];
  const int tid = threadIdx.x;
  const int lane = tid & 63;
  const int l15 = lane & 15;
  const int rgrp = lane >> 4;
  const int kg = lane >> 4;
  const int wid = tid >> 6;        // 0..7
  const int row0 = blockIdx.x * TB;
  const char* wpB = reinterpret_cast<const char*>(wp);

  // ---- phase 0: xs = [x, sin x, cos x, 0, 0] bf16, rows 128B swizzled ----
  for (int i = tid; i < TB * 10; i += NTHREADS) {
    const int r = i / 10, c = i % 10;
    const float xv = x[(size_t)(row0 + r) * 10 + c];
    const int sw = (r & 7) << 4;
    char* rowp = lds + XS_OFF + r * 128;
    *reinterpret_cast<u16*>(rowp + ((c * 2) ^ sw)) = f2bf(xv);
    *reinterpret_cast<u16*>(rowp + (((c + 10) * 2) ^ sw)) = f2bf(__sinf(xv));
    *reinterpret_cast<u16*>(rowp + (((c + 20) * 2) ^ sw)) = f2bf(__cosf(xv));
  }
  for (int i = tid; i < TB * 2; i += NTHREADS) {
    const int r = i >> 1, c = 30 + (i & 1);
    *reinterpret_cast<u16*>(lds + XS_OFF + r * 128 + ((c * 2) ^ ((r & 7) << 4))) = 0;
  }
  __syncthreads();

  // ---- L1: h = relu(xs @ W1 + b1), K=32(pad) ----
  {
    f32x4 acc[4][4];
    gemm_reg<4, 4, 1>(lds, XS_OFF, 128, 0, 0,
                      wpB + (size_t)P_L1 * 2, 8192, 512, wid * 64, kg, l15, acc);
    epi_bb(lds, acc, b1, 512, true, false, tid);   // h-write vs xs-read disjoint
    __syncthreads();
  }
  // ---- L2: relu, L3: relu+concat, L4: no relu ----
  {
    f32x4 acc[4][4];
    gemm_reg<4, 4, 16>(lds, H_OFF, 1024, 0, 0,
                       wpB + (size_t)P_L2 * 2, 32768, 512, wid * 64, kg, l15, acc);
    __syncthreads();
    epi_bb(lds, acc, b2, 512, true, false, tid);
    __syncthreads();
  }
  {
    f32x4 acc[4][4];
    gemm_reg<4, 4, 16>(lds, H_OFF, 1024, 0, 0,
                       wpB + (size_t)P_L3 * 2, 32768, 512, wid * 64, kg, l15, acc);
    __syncthreads();
    epi_bb(lds, acc, b3, 482, true, true, tid);
    __syncthreads();
  }
  {
    f32x4 acc[4][4];
    gemm_reg<4, 4, 16>(lds, H_OFF, 1024, 0, 0,
                       wpB + (size_t)P_L4 * 2, 32768, 512, wid * 64, kg, l15, acc);
    __syncthreads();
    epi_bb(lds, acc, b4, 512, false, false, tid);
    __syncthreads();
  }

  // ---- heads: per grp, H1 col-split (B read-once) then wave-private H2+ ----
  {
    const int half = wid & 1;        // row-half for H2..H5
    const int mB = half * 32;
    for (int grp = 0; grp < 2; ++grp) {
      if (grp) __syncthreads();      // grp0 slice readers done before overwrite

      // H1: wave = (head h4=wid>>1, colhalf=wid&1), fm=4 over ALL 64 rows.
      // Each B line read exactly once per block.
      {
        const int h4 = wid >> 1, colhalf = wid & 1;
        const int g1 = grp * 4 + h4;
        const int pair1 = g1 >> 1, side1 = g1 & 1;
        const int y1o1 = Y1_OFF + (g1 & 3) * 16384;
        f32x4 acc[4][4];
        gemm_reg<4, 4, 16>(lds, H_OFF, 1024, 0, 0,
                           wpB + (size_t)P_H1 * 2 + (size_t)pair1 * 262144, 16384, 256,
                           side1 * 128 + colhalf * 64, kg, l15, acc);
#pragma unroll
        for (int fj = 0; fj < 4; ++fj) {
          const int c = colhalf * 64 + fj * 16 + l15;       // 0..127 in head
          const float bv = Hb1[g1 * 128 + c];
#pragma unroll
          for (int fi = 0; fi < 4; ++fi)
#pragma unroll
            for (int r = 0; r < 4; ++r) {
              const int m = fi * 16 + rgrp * 4 + r;
              const float v = fmaxf(acc[fi][fj][r] + bv, 0.f);
              *reinterpret_cast<u16*>(lds + y1o1 + m * 256 + ((c * 2) ^ ((m & 7) << 4))) = f2bf(v);
            }
        }
      }
      __syncthreads();               // y1 slices complete

      // H2..H5: wave = (head g, row-half); wave-private, no barriers.
      const int g = grp * 4 + (wid >> 1);
      const int pair = g >> 1, side = g & 1;
      const int y1o = Y1_OFF + (g & 3) * 16384;
      const int scrOff = y1o + half * 8192;     // this wave's 32 rows
      char* scr = lds + scrOff;

      // H2: y2[32][64] = relu(y1_own_rows @ HW2[g] + Hb2[g]), K=128
      {
        f32x4 a2[2][4];
        gemm_reg<2, 4, 4>(lds, scrOff, 256, 0, 0,
                          wpB + (size_t)P_H2 * 2 + (size_t)pair * 32768, 8192, 128,
                          side * 64, kg, l15, a2);
#pragma unroll
        for (int fj = 0; fj < 4; ++fj) {
          const int c = fj * 16 + l15;
          const float bv = Hb2[g * 64 + c];
#pragma unroll
          for (int fi = 0; fi < 2; ++fi)
#pragma unroll
            for (int r = 0; r < 4; ++r) {
              const int rl = fi * 16 + rgrp * 4 + r;
              const float v = fmaxf(a2[fi][fj][r] + bv, 0.f);
              *reinterpret_cast<u16*>(scr + rl * 256 + ((c * 2) ^ ((rl & 7) << 4))) = f2bf(v);
            }
        }
      }
      // H3: y3[32][32] = relu(y2 @ HW3[g] + Hb3[g]), K=64
      {
        f32x4 a3[2][2];
        gemm_reg<2, 2, 2>(lds, scrOff, 256, 0, 0,
                          wpB + (size_t)P_H3 * 2 + (size_t)pair * 8192, 4096, 64,
                          side * 32, kg, l15, a3);
#pragma unroll
        for (int fj = 0; fj < 2; ++fj) {
          const int c = fj * 16 + l15;
          const float bv = Hb3[g * 32 + c];
#pragma unroll
          for (int fi = 0; fi < 2; ++fi)
#pragma unroll
            for (int r = 0; r < 4; ++r) {
              const int rl = fi * 16 + rgrp * 4 + r;
              const float v = fmaxf(a3[fi][fj][r] + bv, 0.f);
              *reinterpret_cast<u16*>(scr + rl * 256 + ((c * 2) ^ ((rl & 7) << 4))) = f2bf(v);
            }
        }
      }
      // H4: y4[32][16] = relu(y3 @ HW4[g] + Hb4[g]), K=32
      {
        f32x4 a4[2][1];
        gemm_reg<2, 1, 1>(lds, scrOff, 256, 0, 0,
                          wpB + (size_t)P_H4 * 2 + (size_t)pair * 2048, 2048, 32,
                          side * 16, kg, l15, a4);
        const int c = l15;
        const float bv = Hb4[g * 16 + c];
#pragma unroll
        for (int fi = 0; fi < 2; ++fi)
#pragma unroll
          for (int r = 0; r < 4; ++r) {
            const int rl = fi * 16 + rgrp * 4 + r;
            const float v = fmaxf(a4[fi][0][r] + bv, 0.f);
            *reinterpret_cast<u16*>(scr + rl * 256 + ((c * 2) ^ ((rl & 7) << 4))) = f2bf(v);
          }
      }
      // H5: out[row][g] = y4 @ HW5[g] + Hb5[g]  (two 8-wide lane partials)
      {
        const int r = lane & 31, kh = lane >> 5;
        const s16x8 y4v = *reinterpret_cast<const s16x8*>(
            scr + r * 256 + ((kh * 16) ^ ((r & 7) << 4)));
        float partial = 0.f;
#pragma unroll
        for (int j = 0; j < 8; ++j)
          partial += bf2f((u16)y4v[j]) * hw5[g * 16 + kh * 8 + j];
        partial += __shfl_xor(partial, 32, 64);
        if (kh == 0)
          out[(size_t)(row0 + mB + r) * 8 + g] = Hb5[g] + partial;
      }
    }
  }
}

extern "C" void kernel_launch(void* const* d_in, const int* in_sizes, int n_in,
                              void* d_out, int out_size, void* d_ws, size_t ws_size,
                              hipStream_t stream) {
  (void)in_sizes; (void)n_in; (void)out_size; (void)ws_size;
  const float* x   = (const float*)d_in[0];
  const float* W1  = (const float*)d_in[1];
  const float* b1  = (const float*)d_in[2];
  const float* W2  = (const float*)d_in[3];
  const float* b2  = (const float*)d_in[4];
  const float* W3  = (const float*)d_in[5];
  const float* b3  = (const float*)d_in[6];
  const float* W4  = (const float*)d_in[7];
  const float* b4  = (const float*)d_in[8];
  const float* HW1 = (const float*)d_in[9];
  const float* Hb1 = (const float*)d_in[10];
  const float* HW2 = (const float*)d_in[11];
  const float* Hb2 = (const float*)d_in[12];
  const float* HW3 = (const float*)d_in[13];
  const float* Hb3 = (const float*)d_in[14];
  const float* HW4 = (const float*)d_in[15];
  const float* Hb4 = (const float*)d_in[16];
  const float* HW5 = (const float*)d_in[17];
  const float* Hb5 = (const float*)d_in[18];
  float* out = (float*)d_out;
  u16* wp = (u16*)d_ws;

  prep_weights<<<2048, 256, 0, stream>>>(W1, W2, W3, W4, HW1, HW2, HW3, HW4, wp);

  hipFuncSetAttribute((const void*)fused_mlp,
                      hipFuncAttributeMaxDynamicSharedMemorySize, LDS_BYTES);
  fused_mlp<<<131072 / TB, NTHREADS, LDS_BYTES, stream>>>(
      x, wp, b1, b2, b3, b4, Hb1, Hb2, Hb3, Hb4, HW5, Hb5, out);
}